// Round 2
// baseline (788.348 us; speedup 1.0000x reference)
//
#include <hip/hip_runtime.h>

#define NPOS 262144  // 512*512

typedef __attribute__((ext_vector_type(8))) short short8;
typedef __attribute__((ext_vector_type(4))) float f32x4;
typedef __attribute__((ext_vector_type(4))) unsigned short us4;
typedef __attribute__((ext_vector_type(4))) unsigned int u32x4;

__device__ __forceinline__ unsigned short f2bf(float f){
  unsigned u = __float_as_uint(f);
  u += 0x7fffu + ((u >> 16) & 1u);
  return (unsigned short)(u >> 16);
}
__device__ __forceinline__ float bf2f(unsigned int h){ return __uint_as_float(h << 16); }
__device__ __forceinline__ float sigm(float x){ return 1.f/(1.f + __expf(-x)); }

#define MFMA16(a,b,c) __builtin_amdgcn_mfma_f32_16x16x32_bf16((a),(b),(c),0,0,0)

// ---------------------------------------------------------------------------
// Prep: fold LN gains into weights. Wc rows: [0,256)=W_lr', [256,512)=W_gate',
// [512,640)=W_og', [640,768)=W_out'.  svec[r]=sum(g*W_row), cvec[r]=sum(b*W_row)+bias.
// ---------------------------------------------------------------------------
__global__ __launch_bounds__(256) void k_prep(
    const float* __restrict__ Wlr, const float* __restrict__ b_lr,
    const float* __restrict__ Wg,  const float* __restrict__ b_g,
    const float* __restrict__ Wog, const float* __restrict__ b_og,
    const float* __restrict__ Wout,const float* __restrict__ obias,
    const float* __restrict__ g1, const float* __restrict__ b1,
    const float* __restrict__ g2, const float* __restrict__ b2,
    unsigned short* __restrict__ Wc, float* __restrict__ svec, float* __restrict__ cvec)
{
  int r = blockIdx.x*4 + (threadIdx.x >> 6);
  int l = threadIdx.x & 63;
  const float *W, *gv, *bv; float extra;
  if (r < 256)      { W = Wlr + r*128;         extra = b_lr[r];      gv=g1; bv=b1; }
  else if (r < 512) { W = Wg  + (r-256)*128;   extra = b_g[r-256];   gv=g1; bv=b1; }
  else if (r < 640) { W = Wog + (r-512)*128;   extra = b_og[r-512];  gv=g1; bv=b1; }
  else              { W = Wout+ (r-640)*128;   extra = obias[r-640]; gv=g2; bv=b2; }
  float w0 = W[2*l], w1 = W[2*l+1];
  float p0 = w0 * gv[2*l], p1 = w1 * gv[2*l+1];
  float s  = p0 + p1;
  float cc = w0 * bv[2*l] + w1 * bv[2*l+1];
  Wc[r*128 + 2*l]   = f2bf(p0);
  Wc[r*128 + 2*l+1] = f2bf(p1);
  for (int off=32; off; off>>=1){ s += __shfl_down(s, off); cc += __shfl_down(cc, off); }
  if (l == 0){ svec[r] = s; cvec[r] = cc + extra; }
}

// ---------------------------------------------------------------------------
// Proj: per block = 64 positions (grid 4096). LDS 27.9KB -> 4 blocks/CU
// (launch_bounds(256,4)). zt pitch 144 (72 dwords — empirically conflict-free
// for the b128 A-reads; 68-dword pitch measured 2M conflicts). LN1 stats via
// 32-lane shfl_xor butterfly during staging. N chunked (np): acc = 32 VGPR.
// ---------------------------------------------------------------------------
__global__ __launch_bounds__(256, 4) void k_proj(
    const float* __restrict__ Zraw, const float* __restrict__ Zmask,
    const unsigned short* __restrict__ Wc,
    const float* __restrict__ svec, const float* __restrict__ cvec,
    unsigned short* __restrict__ leftT, unsigned short* __restrict__ rightT)
{
  __shared__ unsigned short zt[64*144];    // 18432 B, pitch 144 (known conflict-free)
  __shared__ unsigned short tlc[64*68];    // 8704 B transpose chunk [col][pos]
  __shared__ float mu_s[64], rs_s[64], mask_s[64];
  const int t = threadIdx.x, l = t & 63, w = t >> 6;
  const int wr = w >> 1, wc = w & 1;
  const long pos0 = (long)blockIdx.x * 64;

  if (t < 64) mask_s[t] = Zmask[pos0 + t];
  { const f32x4* zg = (const f32x4*)(Zraw + pos0*128);
    f32x4 zv[8];
    #pragma unroll
    for (int v=0; v<8; v++) zv[v] = zg[v*256 + t];
    #pragma unroll
    for (int v=0; v<8; v++){
      int f = v*256 + t, row = f>>5, c4 = f&31;
      f32x4 z = zv[v];
      us4 h; h[0]=f2bf(z[0]); h[1]=f2bf(z[1]); h[2]=f2bf(z[2]); h[3]=f2bf(z[3]);
      *(us4*)&zt[row*144 + c4*4] = h;
      // each 32-lane half covers one full 128-chan row -> butterfly reduce
      float s  = (z[0]+z[1]) + (z[2]+z[3]);
      float ss = (z[0]*z[0]+z[1]*z[1]) + (z[2]*z[2]+z[3]*z[3]);
      #pragma unroll
      for (int off=16; off; off>>=1){ s += __shfl_xor(s, off); ss += __shfl_xor(ss, off); }
      if ((l&31) == 0){
        float mu = s * 0.0078125f;
        float var = ss * 0.0078125f - mu*mu;
        mu_s[row] = mu; rs_s[row] = rsqrtf(var + 1e-5f);
      }
    }
  }
  __syncthreads();

  for (int half=0; half<2; half++){
    for (int np=0; np<2; np++){
      const unsigned short* Blr = Wc + (half*128 + np*64 + wc*32)*128;
      const unsigned short* Bgt = Blr + 256*128;
      f32x4 accL[2][2], accG[2][2];
      #pragma unroll
      for (int mt=0; mt<2; mt++)
        #pragma unroll
        for (int nt=0; nt<2; nt++){
          accL[mt][nt] = (f32x4)(0.f); accG[mt][nt] = (f32x4)(0.f);
        }
      #pragma unroll
      for (int ks=0; ks<4; ks++){
        const int krow = ks*32 + ((l>>4)<<3);
        short8 bl[2], bg[2];
        #pragma unroll
        for (int nt=0; nt<2; nt++){
          int n = nt*16 + (l&15);
          bl[nt] = *(const short8*)(Blr + n*128 + krow);
          bg[nt] = *(const short8*)(Bgt + n*128 + krow);
        }
        #pragma unroll
        for (int mt=0; mt<2; mt++){
          int row = wr*32 + mt*16 + (l&15);
          short8 a = *(const short8*)&zt[row*144 + krow];
          #pragma unroll
          for (int nt=0; nt<2; nt++){
            accL[mt][nt] = MFMA16(a, bl[nt], accL[mt][nt]);
            accG[mt][nt] = MFMA16(a, bg[nt], accG[mt][nt]);
          }
        }
      }
      // epilogue for this np's 64 cols
      {
        int cbase = wc*32 + (l&15);
        int nn0 = np*64 + cbase, nn1 = nn0 + 16;
        float sL0 = svec[half*128 + nn0], cL0 = cvec[half*128 + nn0];
        float sL1 = svec[half*128 + nn1], cL1 = cvec[half*128 + nn1];
        float sG0 = svec[256 + half*128 + nn0], cG0 = cvec[256 + half*128 + nn0];
        float sG1 = svec[256 + half*128 + nn1], cG1 = cvec[256 + half*128 + nn1];
        #pragma unroll
        for (int mt=0; mt<2; mt++){
          int rowb = wr*32 + mt*16 + ((l>>4)<<2);
          us4 h0, h1;
          #pragma unroll
          for (int r=0; r<4; r++){
            int row = rowb + r;
            float rs = rs_s[row], rm = rs*mu_s[row], mk = mask_s[row];
            float l0 = rs*accL[mt][0][r] - rm*sL0 + cL0;
            float g0 = sigm(rs*accG[mt][0][r] - rm*sG0 + cG0);
            h0[r] = f2bf(mk * l0 * g0);
            float l1 = rs*accL[mt][1][r] - rm*sL1 + cL1;
            float g1 = sigm(rs*accG[mt][1][r] - rm*sG1 + cG1);
            h1[r] = f2bf(mk * l1 * g1);
          }
          *(us4*)&tlc[cbase*68 + rowb] = h0;
          *(us4*)&tlc[(cbase+16)*68 + rowb] = h1;
        }
      }
      __syncthreads();
      unsigned short* dst = half ? rightT : leftT;
      #pragma unroll
      for (int v=0; v<8; v++){
        int f2 = v*256 + t, cc = f2>>5, rp = (f2&31)<<1;
        unsigned u = *(const unsigned*)&tlc[cc*68 + rp];
        *(unsigned*)&dst[(long)(np*64 + cc)*NPOS + pos0 + rp] = u;
      }
      __syncthreads();
    }
  }
}

// ---------------------------------------------------------------------------
// Triangle: 128 per-channel GEMMs P_c = L_c * R_c^T (512^3 each).
// pj aliases At/Bt (disjoint in time, separated by barrier): LDS 71KB -> 36.9KB
// -> 4 blocks/CU. XCD-aware swizzle: each XCD owns 16 channels so concurrent
// blocks share L_c/R_c panels in its private L2.
// ---------------------------------------------------------------------------
__global__ __launch_bounds__(256, 4) void k_tri(
    const unsigned short* __restrict__ leftT, const unsigned short* __restrict__ rightT,
    unsigned short* __restrict__ pP)
{
  __shared__ unsigned short smem[2*128*72];           // At | Bt ; pj aliases (33792 <= 36864)
  unsigned short* At = smem;
  unsigned short* Bt = smem + 128*72;
  unsigned short* pj = smem;
  const int t = threadIdx.x, l = t & 63, w = t >> 6;
  const int wr = w >> 1, wc = w & 1;
  const int bid = blockIdx.x;
  const int xcd = bid & 7, q = bid >> 3;
  const int c = (xcd << 4) | (q & 15);
  const int tile = q >> 4;
  const int ti = (tile >> 2) << 7, tj = (tile & 3) << 7;
  const unsigned short* L = leftT  + (long)c*NPOS + (long)ti*512;
  const unsigned short* R = rightT + (long)c*NPOS + (long)tj*512;
  f32x4 acc[4][4];
  for (int mt=0; mt<4; mt++) for (int nt=0; nt<4; nt++) acc[mt][nt] = (f32x4)(0.f);
  for (int kt=0; kt<8; kt++){
    const int k0 = kt*64;
    __syncthreads();
    for (int v=0; v<4; v++){
      int f = v*256 + t, row = f>>3, kc = f&7;
      *(u32x4*)&At[row*72 + kc*8] = *(const u32x4*)(L + row*512 + k0 + kc*8);
      *(u32x4*)&Bt[row*72 + kc*8] = *(const u32x4*)(R + row*512 + k0 + kc*8);
    }
    __syncthreads();
    for (int ks2=0; ks2<2; ks2++){
      const int krow = ks2*32 + ((l>>4)<<3);
      short8 br[4];
      for (int nt=0; nt<4; nt++)
        br[nt] = *(const short8*)&Bt[(wc*64 + nt*16 + (l&15))*72 + krow];
      for (int mt=0; mt<4; mt++){
        short8 a = *(const short8*)&At[(wr*64 + mt*16 + (l&15))*72 + krow];
        for (int nt=0; nt<4; nt++)
          acc[mt][nt] = MFMA16(a, br[nt], acc[mt][nt]);
      }
    }
  }
  __syncthreads();   // all waves done reading At/Bt -> safe to alias as pj
  for (int mt=0; mt<4; mt++){
    int rowb = wr*64 + mt*16 + ((l>>4)<<2);
    for (int nt=0; nt<4; nt++){
      int col = wc*64 + nt*16 + (l&15);
      for (int r=0; r<4; r++)
        pj[(rowb+r)*132 + col] = f2bf(acc[mt][nt][r]);
    }
  }
  __syncthreads();
  unsigned short* dst = pP + (long)c*NPOS + (long)ti*512 + tj;
  for (int v=0; v<32; v++){
    int f2 = v*256 + t, row = f2>>6, cp = (f2&63)<<1;
    unsigned u = *(const unsigned*)&pj[row*132 + cp];
    *(unsigned*)&dst[(long)row*512 + cp] = u;
  }
}

// ---------------------------------------------------------------------------
// Out: per block = 128 positions (one i, 128 j). zt staging DROPPED: gate
// A-fragments converted from global f32 Zraw in-register; LN1 stats via
// staging-butterfly; LN2 partials folded into pt staging. LDS 39.4KB ->
// 4 blocks/CU; N chunked (np) -> acc 64 VGPR, launch_bounds(256,3).
// ---------------------------------------------------------------------------
__global__ __launch_bounds__(256, 3) void k_out(
    const float* __restrict__ Zraw, const unsigned short* __restrict__ pP,
    const unsigned short* __restrict__ Wc,
    const float* __restrict__ svec, const float* __restrict__ cvec,
    float* __restrict__ out)
{
  __shared__ unsigned pt[128*65];          // p bf16 [c][j], 65-dword pitch (33280 B)
  __shared__ float sb[256*4];              // LN2 partials (4096 B)
  __shared__ float mu1s[128], rs1s[128], mu2s[128], rs2s[128];  // 2048 B
  const int t = threadIdx.x, l = t & 63, w = t >> 6;
  const int wr = w >> 1, wc = w & 1;
  const long pos0 = (long)blockIdx.x * 128;
  const int ib = blockIdx.x >> 2, j0 = (blockIdx.x & 3) << 7;

  // stage p tile + fold LN2 per-lane partials (each lane: j-pair l, channels w,4+w,...)
  float s0=0.f, ss0=0.f, s1=0.f, ss1=0.f;
  #pragma unroll
  for (int v=0; v<32; v++){
    int f = v*256 + t, cch = f>>6, j2 = f&63;
    unsigned u = *(const unsigned*)&pP[(long)cch*NPOS + (long)ib*512 + j0 + 2*j2];
    pt[cch*65 + j2] = u;
    float a = bf2f(u & 0xffffu), b = bf2f(u >> 16);
    s0 += a; ss0 += a*a; s1 += b; ss1 += b*b;
  }
  // LN1 row stats straight from global Zraw via butterfly (no zt staging)
  { const f32x4* zg = (const f32x4*)(Zraw + pos0*128);
    #pragma unroll
    for (int v=0; v<16; v++){
      int f = v*256 + t, row = f>>5;
      f32x4 z = zg[f];
      float s  = (z[0]+z[1]) + (z[2]+z[3]);
      float ss = (z[0]*z[0]+z[1]*z[1]) + (z[2]*z[2]+z[3]*z[3]);
      #pragma unroll
      for (int off=16; off; off>>=1){ s += __shfl_xor(s, off); ss += __shfl_xor(ss, off); }
      if ((l&31) == 0){
        float mu = s * 0.0078125f;
        float var = ss * 0.0078125f - mu*mu;
        mu1s[row] = mu; rs1s[row] = rsqrtf(var + 1e-5f);
      }
    }
  }
  sb[t*4+0] = s0; sb[t*4+1] = ss0; sb[t*4+2] = s1; sb[t*4+3] = ss1;
  __syncthreads();
  if (t < 128){
    int j = t, jpp = j >> 1, o = j & 1;
    float S=0.f, SS=0.f;
    #pragma unroll
    for (int ww=0; ww<4; ww++){
      S  += sb[(ww*64 + jpp)*4 + 2*o];
      SS += sb[(ww*64 + jpp)*4 + 2*o + 1];
    }
    float mu = S*0.0078125f, var = SS*0.0078125f - mu*mu;
    mu2s[j] = mu; rs2s[j] = rsqrtf(var + 1e-5f);
  }
  __syncthreads();

  const unsigned short* pt16 = (const unsigned short*)pt;
  const float* zbase = Zraw + pos0*128;
  for (int np=0; np<2; np++){
    f32x4 acc1[4][2], acc2[4][2];
    #pragma unroll
    for (int mt=0; mt<4; mt++)
      #pragma unroll
      for (int nt=0; nt<2; nt++){
        acc1[mt][nt]=(f32x4)(0.f); acc2[mt][nt]=(f32x4)(0.f);
      }
    #pragma unroll
    for (int ks=0; ks<4; ks++){
      const int krow = ks*32 + ((l>>4)<<3);
      short8 bo[2], bg[2];
      #pragma unroll
      for (int nt=0; nt<2; nt++){
        int n = np*64 + wc*32 + nt*16 + (l&15);
        bo[nt] = *(const short8*)(Wc + (640+n)*128 + krow);
        bg[nt] = *(const short8*)(Wc + (512+n)*128 + krow);
      }
      #pragma unroll
      for (int mt=0; mt<4; mt++){
        int row = wr*64 + mt*16 + (l&15);
        // A-frag for out GEMM: gather 8 channels (krow..krow+7) of column j=row
        short8 ap;
        #pragma unroll
        for (int m=0; m<8; m++)
          ap[m] = (short)pt16[(krow+m)*130 + row];
        // A-frag for gate GEMM: convert from global f32 Zraw in-register
        const float* zp = zbase + row*128 + krow;
        f32x4 za = *(const f32x4*)zp, zb2 = *(const f32x4*)(zp+4);
        short8 az;
        az[0]=(short)f2bf(za[0]); az[1]=(short)f2bf(za[1]);
        az[2]=(short)f2bf(za[2]); az[3]=(short)f2bf(za[3]);
        az[4]=(short)f2bf(zb2[0]); az[5]=(short)f2bf(zb2[1]);
        az[6]=(short)f2bf(zb2[2]); az[7]=(short)f2bf(zb2[3]);
        #pragma unroll
        for (int nt=0; nt<2; nt++){
          acc1[mt][nt] = MFMA16(ap, bo[nt], acc1[mt][nt]);
          acc2[mt][nt] = MFMA16(az, bg[nt], acc2[mt][nt]);
        }
      }
    }
    // epilogue for this np's 64 output channels
    int cbase = np*64 + wc*32 + (l&15);
    float sO0 = svec[640 + cbase],      cO0 = cvec[640 + cbase];
    float sO1 = svec[640 + cbase + 16], cO1 = cvec[640 + cbase + 16];
    float sg0 = svec[512 + cbase],      cg0 = cvec[512 + cbase];
    float sg1 = svec[512 + cbase + 16], cg1 = cvec[512 + cbase + 16];
    #pragma unroll
    for (int mt=0; mt<4; mt++){
      int rowb = wr*64 + mt*16 + ((l>>4)<<2);
      #pragma unroll
      for (int r=0; r<4; r++){
        int row = rowb + r;
        float rs2 = rs2s[row], rm2 = rs2*mu2s[row];
        float rs1 = rs1s[row], rm1 = rs1*mu1s[row];
        long gidx = (pos0 + row)*128;
        float ab0 = rs2*acc1[mt][0][r] - rm2*sO0 + cO0;
        float gv0 = sigm(rs1*acc2[mt][0][r] - rm1*sg0 + cg0);
        out[gidx + cbase] = Zraw[gidx + cbase] + gv0*ab0;
        float ab1 = rs2*acc1[mt][1][r] - rm2*sO1 + cO1;
        float gv1 = sigm(rs1*acc2[mt][1][r] - rm1*sg1 + cg1);
        out[gidx + cbase + 16] = Zraw[gidx + cbase + 16] + gv1*ab1;
      }
    }
  }
}

// ---------------------------------------------------------------------------
extern "C" void kernel_launch(void* const* d_in, const int* in_sizes, int n_in,
                              void* d_out, int out_size, void* d_ws, size_t ws_size,
                              hipStream_t stream)
{
  (void)in_sizes; (void)n_in; (void)out_size; (void)ws_size;
  const float* Zraw  = (const float*)d_in[0];
  const float* Zmask = (const float*)d_in[1];
  const float* g1    = (const float*)d_in[2];
  const float* b1    = (const float*)d_in[3];
  const float* Wlr   = (const float*)d_in[4];
  const float* blr   = (const float*)d_in[5];
  const float* Wg    = (const float*)d_in[6];
  const float* bg    = (const float*)d_in[7];
  const float* Wog   = (const float*)d_in[8];
  const float* bog   = (const float*)d_in[9];
  const float* g2    = (const float*)d_in[10];
  const float* b2    = (const float*)d_in[11];
  const float* Wout  = (const float*)d_in[12];
  const float* obias = (const float*)d_in[13];

  char* ws = (char*)d_ws;
  unsigned short* leftT  = (unsigned short*)(ws);
  unsigned short* rightT = (unsigned short*)(ws + 67108864L);
  unsigned short* pP     = (unsigned short*)(ws + 134217728L);
  unsigned short* Wc     = (unsigned short*)(ws + 201326592L);
  float* svec            = (float*)(ws + 201326592L + 196608L);
  float* cvec            = (float*)(ws + 201326592L + 196608L + 4096L);
  float* out = (float*)d_out;

  k_prep<<<192, 256, 0, stream>>>(Wlr, blr, Wg, bg, Wog, bog, Wout, obias,
                                  g1, b1, g2, b2, Wc, svec, cvec);
  k_proj<<<4096, 256, 0, stream>>>(Zraw, Zmask, Wc, svec, cvec, leftT, rightT);
  k_tri<<<2048, 256, 0, stream>>>(leftT, rightT, pP);
  k_out<<<2048, 256, 0, stream>>>(Zraw, pP, Wc, svec, cvec, out);
}

// Round 4
// 698.689 us; speedup vs baseline: 1.1283x; 1.1283x over previous
//
#include <hip/hip_runtime.h>

#define NPOS 262144  // 512*512

typedef __attribute__((ext_vector_type(8))) short short8;
typedef __attribute__((ext_vector_type(4))) float f32x4;
typedef __attribute__((ext_vector_type(4))) unsigned short us4;
typedef __attribute__((ext_vector_type(4))) unsigned int u32x4;

__device__ __forceinline__ unsigned short f2bf(float f){
  unsigned u = __float_as_uint(f);
  u += 0x7fffu + ((u >> 16) & 1u);
  return (unsigned short)(u >> 16);
}
__device__ __forceinline__ float bf2f(unsigned int h){ return __uint_as_float(h << 16); }
__device__ __forceinline__ float sigm(float x){ return 1.f/(1.f + __expf(-x)); }

#define MFMA16(a,b,c) __builtin_amdgcn_mfma_f32_16x16x32_bf16((a),(b),(c),0,0,0)

// ---------------------------------------------------------------------------
// Prep: fold LN gains into weights. Wc rows: [0,256)=W_lr', [256,512)=W_gate',
// [512,640)=W_og', [640,768)=W_out'.  svec[r]=sum(g*W_row), cvec[r]=sum(b*W_row)+bias.
// ---------------------------------------------------------------------------
__global__ __launch_bounds__(256) void k_prep(
    const float* __restrict__ Wlr, const float* __restrict__ b_lr,
    const float* __restrict__ Wg,  const float* __restrict__ b_g,
    const float* __restrict__ Wog, const float* __restrict__ b_og,
    const float* __restrict__ Wout,const float* __restrict__ obias,
    const float* __restrict__ g1, const float* __restrict__ b1,
    const float* __restrict__ g2, const float* __restrict__ b2,
    unsigned short* __restrict__ Wc, float* __restrict__ svec, float* __restrict__ cvec)
{
  int r = blockIdx.x*4 + (threadIdx.x >> 6);
  int l = threadIdx.x & 63;
  const float *W, *gv, *bv; float extra;
  if (r < 256)      { W = Wlr + r*128;         extra = b_lr[r];      gv=g1; bv=b1; }
  else if (r < 512) { W = Wg  + (r-256)*128;   extra = b_g[r-256];   gv=g1; bv=b1; }
  else if (r < 640) { W = Wog + (r-512)*128;   extra = b_og[r-512];  gv=g1; bv=b1; }
  else              { W = Wout+ (r-640)*128;   extra = obias[r-640]; gv=g2; bv=b2; }
  float w0 = W[2*l], w1 = W[2*l+1];
  float p0 = w0 * gv[2*l], p1 = w1 * gv[2*l+1];
  float s  = p0 + p1;
  float cc = w0 * bv[2*l] + w1 * bv[2*l+1];
  Wc[r*128 + 2*l]   = f2bf(p0);
  Wc[r*128 + 2*l+1] = f2bf(p1);
  for (int off=32; off; off>>=1){ s += __shfl_down(s, off); cc += __shfl_down(cc, off); }
  if (l == 0){ svec[r] = s; cvec[r] = cc + extra; }
}

// ---------------------------------------------------------------------------
// Proj: per block = 64 positions (grid 4096). LDS 27.9KB -> 4 blocks/CU.
// zt pitch 144 (72 dwords, empirically conflict-free for b128 A-reads).
// LN1 stats via 32-lane shfl_xor butterfly during staging. np-split acc.
// ---------------------------------------------------------------------------
__global__ __launch_bounds__(256, 4) void k_proj(
    const float* __restrict__ Zraw, const float* __restrict__ Zmask,
    const unsigned short* __restrict__ Wc,
    const float* __restrict__ svec, const float* __restrict__ cvec,
    unsigned short* __restrict__ leftT, unsigned short* __restrict__ rightT)
{
  __shared__ unsigned short zt[64*144];    // 18432 B
  __shared__ unsigned short tlc[64*68];    // 8704 B transpose chunk [col][pos]
  __shared__ float mu_s[64], rs_s[64], mask_s[64];
  const int t = threadIdx.x, l = t & 63, w = t >> 6;
  const int wr = w >> 1, wc = w & 1;
  const long pos0 = (long)blockIdx.x * 64;

  if (t < 64) mask_s[t] = Zmask[pos0 + t];
  { const f32x4* zg = (const f32x4*)(Zraw + pos0*128);
    f32x4 zv[8];
    #pragma unroll
    for (int v=0; v<8; v++) zv[v] = zg[v*256 + t];
    #pragma unroll
    for (int v=0; v<8; v++){
      int f = v*256 + t, row = f>>5, c4 = f&31;
      f32x4 z = zv[v];
      us4 h; h[0]=f2bf(z[0]); h[1]=f2bf(z[1]); h[2]=f2bf(z[2]); h[3]=f2bf(z[3]);
      *(us4*)&zt[row*144 + c4*4] = h;
      float s  = (z[0]+z[1]) + (z[2]+z[3]);
      float ss = (z[0]*z[0]+z[1]*z[1]) + (z[2]*z[2]+z[3]*z[3]);
      #pragma unroll
      for (int off=16; off; off>>=1){ s += __shfl_xor(s, off); ss += __shfl_xor(ss, off); }
      if ((l&31) == 0){
        float mu = s * 0.0078125f;
        float var = ss * 0.0078125f - mu*mu;
        mu_s[row] = mu; rs_s[row] = rsqrtf(var + 1e-5f);
      }
    }
  }
  __syncthreads();

  for (int half=0; half<2; half++){
    for (int np=0; np<2; np++){
      const unsigned short* Blr = Wc + (half*128 + np*64 + wc*32)*128;
      const unsigned short* Bgt = Blr + 256*128;
      f32x4 accL[2][2], accG[2][2];
      #pragma unroll
      for (int mt=0; mt<2; mt++)
        #pragma unroll
        for (int nt=0; nt<2; nt++){
          accL[mt][nt] = (f32x4)(0.f); accG[mt][nt] = (f32x4)(0.f);
        }
      #pragma unroll
      for (int ks=0; ks<4; ks++){
        const int krow = ks*32 + ((l>>4)<<3);
        short8 bl[2], bg[2];
        #pragma unroll
        for (int nt=0; nt<2; nt++){
          int n = nt*16 + (l&15);
          bl[nt] = *(const short8*)(Blr + n*128 + krow);
          bg[nt] = *(const short8*)(Bgt + n*128 + krow);
        }
        #pragma unroll
        for (int mt=0; mt<2; mt++){
          int row = wr*32 + mt*16 + (l&15);
          short8 a = *(const short8*)&zt[row*144 + krow];
          #pragma unroll
          for (int nt=0; nt<2; nt++){
            accL[mt][nt] = MFMA16(a, bl[nt], accL[mt][nt]);
            accG[mt][nt] = MFMA16(a, bg[nt], accG[mt][nt]);
          }
        }
      }
      {
        int cbase = wc*32 + (l&15);
        int nn0 = np*64 + cbase, nn1 = nn0 + 16;
        float sL0 = svec[half*128 + nn0], cL0 = cvec[half*128 + nn0];
        float sL1 = svec[half*128 + nn1], cL1 = cvec[half*128 + nn1];
        float sG0 = svec[256 + half*128 + nn0], cG0 = cvec[256 + half*128 + nn0];
        float sG1 = svec[256 + half*128 + nn1], cG1 = cvec[256 + half*128 + nn1];
        #pragma unroll
        for (int mt=0; mt<2; mt++){
          int rowb = wr*32 + mt*16 + ((l>>4)<<2);
          us4 h0, h1;
          #pragma unroll
          for (int r=0; r<4; r++){
            int row = rowb + r;
            float rs = rs_s[row], rm = rs*mu_s[row], mk = mask_s[row];
            float l0 = rs*accL[mt][0][r] - rm*sL0 + cL0;
            float g0 = sigm(rs*accG[mt][0][r] - rm*sG0 + cG0);
            h0[r] = f2bf(mk * l0 * g0);
            float l1 = rs*accL[mt][1][r] - rm*sL1 + cL1;
            float g1 = sigm(rs*accG[mt][1][r] - rm*sG1 + cG1);
            h1[r] = f2bf(mk * l1 * g1);
          }
          *(us4*)&tlc[cbase*68 + rowb] = h0;
          *(us4*)&tlc[(cbase+16)*68 + rowb] = h1;
        }
      }
      __syncthreads();
      unsigned short* dst = half ? rightT : leftT;
      #pragma unroll
      for (int v=0; v<8; v++){
        int f2 = v*256 + t, cc = f2>>5, rp = (f2&31)<<1;
        unsigned u = *(const unsigned*)&tlc[cc*68 + rp];
        *(unsigned*)&dst[(long)(np*64 + cc)*NPOS + pos0 + rp] = u;
      }
      __syncthreads();
    }
  }
}

// ---------------------------------------------------------------------------
// Triangle: 128 per-channel GEMMs P_c = L_c * R_c^T (512^3 each).
// pj aliases At/Bt (disjoint in time): LDS 36.9KB -> 4 blocks/CU.
// XCD swizzle: each XCD walks the 16 tiles of one channel consecutively
// (L_c+R_c = 1MB working set in its private L2, 4x reuse per panel quarter).
// ---------------------------------------------------------------------------
__global__ __launch_bounds__(256, 4) void k_tri(
    const unsigned short* __restrict__ leftT, const unsigned short* __restrict__ rightT,
    unsigned short* __restrict__ pP)
{
  __shared__ unsigned short smem[2*128*72];           // At | Bt ; pj aliases
  unsigned short* At = smem;
  unsigned short* Bt = smem + 128*72;
  unsigned short* pj = smem;
  const int t = threadIdx.x, l = t & 63, w = t >> 6;
  const int wr = w >> 1, wc = w & 1;
  const int bid = blockIdx.x;
  const int xcd = bid & 7, q = bid >> 3;
  const int c = (xcd << 4) | (q >> 4);     // channel: 16 per XCD
  const int tile = q & 15;                 // tiles iterate fastest per XCD
  const int ti = (tile >> 2) << 7, tj = (tile & 3) << 7;
  const unsigned short* L = leftT  + (long)c*NPOS + (long)ti*512;
  const unsigned short* R = rightT + (long)c*NPOS + (long)tj*512;
  f32x4 acc[4][4];
  for (int mt=0; mt<4; mt++) for (int nt=0; nt<4; nt++) acc[mt][nt] = (f32x4)(0.f);
  for (int kt=0; kt<8; kt++){
    const int k0 = kt*64;
    __syncthreads();
    for (int v=0; v<4; v++){
      int f = v*256 + t, row = f>>3, kc = f&7;
      *(u32x4*)&At[row*72 + kc*8] = *(const u32x4*)(L + row*512 + k0 + kc*8);
      *(u32x4*)&Bt[row*72 + kc*8] = *(const u32x4*)(R + row*512 + k0 + kc*8);
    }
    __syncthreads();
    for (int ks2=0; ks2<2; ks2++){
      const int krow = ks2*32 + ((l>>4)<<3);
      short8 br[4];
      for (int nt=0; nt<4; nt++)
        br[nt] = *(const short8*)&Bt[(wc*64 + nt*16 + (l&15))*72 + krow];
      for (int mt=0; mt<4; mt++){
        short8 a = *(const short8*)&At[(wr*64 + mt*16 + (l&15))*72 + krow];
        for (int nt=0; nt<4; nt++)
          acc[mt][nt] = MFMA16(a, br[nt], acc[mt][nt]);
      }
    }
  }
  __syncthreads();   // all waves done reading At/Bt -> safe to alias as pj
  for (int mt=0; mt<4; mt++){
    int rowb = wr*64 + mt*16 + ((l>>4)<<2);
    for (int nt=0; nt<4; nt++){
      int col = wc*64 + nt*16 + (l&15);
      for (int r=0; r<4; r++)
        pj[(rowb+r)*132 + col] = f2bf(acc[mt][nt][r]);
    }
  }
  __syncthreads();
  unsigned short* dst = pP + (long)c*NPOS + (long)ti*512 + tj;
  for (int v=0; v<32; v++){
    int f2 = v*256 + t, row = f2>>6, cp = (f2&63)<<1;
    unsigned u = *(const unsigned*)&pj[row*132 + cp];
    *(unsigned*)&dst[(long)row*512 + cp] = u;
  }
}

// ---------------------------------------------------------------------------
// Out: per block = 128 positions (one i, 128 j). zt staging RESTORED (the
// round-2 global A-frag re-reads were the regression: latency-bound scattered
// loads in the MFMA loop, FETCH 594MB). LN1 butterfly during zt staging;
// LN2 partials folded into pt staging (both correctness-verified). np-split
// acc = 64 VGPR. LDS 76.3KB -> 2 blocks/CU, 8 waves (proven regime).
// ---------------------------------------------------------------------------
__global__ __launch_bounds__(256) void k_out(
    const float* __restrict__ Zraw, const unsigned short* __restrict__ pP,
    const unsigned short* __restrict__ Wc,
    const float* __restrict__ svec, const float* __restrict__ cvec,
    float* __restrict__ out)
{
  __shared__ unsigned short zt[128*144];   // Z bf16 [pos][c], 36864 B
  __shared__ unsigned pt[128*65];          // p bf16 [c][j], 65-dw pitch, 33280 B
  __shared__ float sb[256*4];              // LN2 partials
  __shared__ float mu1s[128], rs1s[128], mu2s[128], rs2s[128];
  const int t = threadIdx.x, l = t & 63, w = t >> 6;
  const int wr = w >> 1, wc = w & 1;
  const long pos0 = (long)blockIdx.x * 128;
  const int ib = blockIdx.x >> 2, j0 = (blockIdx.x & 3) << 7;

  // stage zt + LN1 stats via butterfly (each 32-lane half = one full row)
  { const f32x4* zg = (const f32x4*)(Zraw + pos0*128);
    #pragma unroll
    for (int v=0; v<16; v++){
      int f = v*256 + t, row = f>>5, c4 = f&31;
      f32x4 z = zg[f];
      us4 h; h[0]=f2bf(z[0]); h[1]=f2bf(z[1]); h[2]=f2bf(z[2]); h[3]=f2bf(z[3]);
      *(us4*)&zt[row*144 + c4*4] = h;
      float s  = (z[0]+z[1]) + (z[2]+z[3]);
      float ss = (z[0]*z[0]+z[1]*z[1]) + (z[2]*z[2]+z[3]*z[3]);
      #pragma unroll
      for (int off=16; off; off>>=1){ s += __shfl_xor(s, off); ss += __shfl_xor(ss, off); }
      if ((l&31) == 0){
        float mu = s * 0.0078125f;
        float var = ss * 0.0078125f - mu*mu;
        mu1s[row] = mu; rs1s[row] = rsqrtf(var + 1e-5f);
      }
    }
  }
  // stage p tile + fold LN2 per-lane partials
  float s0=0.f, ss0=0.f, s1=0.f, ss1=0.f;
  #pragma unroll
  for (int v=0; v<32; v++){
    int f = v*256 + t, cch = f>>6, j2 = f&63;
    unsigned u = *(const unsigned*)&pP[(long)cch*NPOS + (long)ib*512 + j0 + 2*j2];
    pt[cch*65 + j2] = u;
    float a = bf2f(u & 0xffffu), b = bf2f(u >> 16);
    s0 += a; ss0 += a*a; s1 += b; ss1 += b*b;
  }
  sb[t*4+0] = s0; sb[t*4+1] = ss0; sb[t*4+2] = s1; sb[t*4+3] = ss1;
  __syncthreads();
  if (t < 128){
    int j = t, jpp = j >> 1, o = j & 1;
    float S=0.f, SS=0.f;
    #pragma unroll
    for (int ww=0; ww<4; ww++){
      S  += sb[(ww*64 + jpp)*4 + 2*o];
      SS += sb[(ww*64 + jpp)*4 + 2*o + 1];
    }
    float mu = S*0.0078125f, var = SS*0.0078125f - mu*mu;
    mu2s[j] = mu; rs2s[j] = rsqrtf(var + 1e-5f);
  }
  __syncthreads();

  const unsigned short* pt16 = (const unsigned short*)pt;
  for (int np=0; np<2; np++){
    f32x4 acc1[4][2], acc2[4][2];
    #pragma unroll
    for (int mt=0; mt<4; mt++)
      #pragma unroll
      for (int nt=0; nt<2; nt++){
        acc1[mt][nt]=(f32x4)(0.f); acc2[mt][nt]=(f32x4)(0.f);
      }
    #pragma unroll
    for (int ks=0; ks<4; ks++){
      const int krow = ks*32 + ((l>>4)<<3);
      short8 bo[2], bg[2];
      #pragma unroll
      for (int nt=0; nt<2; nt++){
        int n = np*64 + wc*32 + nt*16 + (l&15);
        bo[nt] = *(const short8*)(Wc + (640+n)*128 + krow);
        bg[nt] = *(const short8*)(Wc + (512+n)*128 + krow);
      }
      #pragma unroll
      for (int mt=0; mt<4; mt++){
        int row = wr*64 + mt*16 + (l&15);
        // A-frag for out GEMM: gather 8 channels (krow..krow+7) of column j=row
        short8 ap;
        #pragma unroll
        for (int m=0; m<8; m++)
          ap[m] = (short)pt16[(krow+m)*130 + row];
        // A-frag for gate GEMM from staged zt
        short8 az = *(const short8*)&zt[row*144 + krow];
        #pragma unroll
        for (int nt=0; nt<2; nt++){
          acc1[mt][nt] = MFMA16(ap, bo[nt], acc1[mt][nt]);
          acc2[mt][nt] = MFMA16(az, bg[nt], acc2[mt][nt]);
        }
      }
    }
    // epilogue for this np's 64 output channels
    int cbase = np*64 + wc*32 + (l&15);
    float sO0 = svec[640 + cbase],      cO0 = cvec[640 + cbase];
    float sO1 = svec[640 + cbase + 16], cO1 = cvec[640 + cbase + 16];
    float sg0 = svec[512 + cbase],      cg0 = cvec[512 + cbase];
    float sg1 = svec[512 + cbase + 16], cg1 = cvec[512 + cbase + 16];
    #pragma unroll
    for (int mt=0; mt<4; mt++){
      int rowb = wr*64 + mt*16 + ((l>>4)<<2);
      #pragma unroll
      for (int r=0; r<4; r++){
        int row = rowb + r;
        float rs2 = rs2s[row], rm2 = rs2*mu2s[row];
        float rs1 = rs1s[row], rm1 = rs1*mu1s[row];
        long gidx = (pos0 + row)*128;
        float ab0 = rs2*acc1[mt][0][r] - rm2*sO0 + cO0;
        float gv0 = sigm(rs1*acc2[mt][0][r] - rm1*sg0 + cg0);
        out[gidx + cbase] = Zraw[gidx + cbase] + gv0*ab0;
        float ab1 = rs2*acc1[mt][1][r] - rm2*sO1 + cO1;
        float gv1 = sigm(rs1*acc2[mt][1][r] - rm1*sg1 + cg1);
        out[gidx + cbase + 16] = Zraw[gidx + cbase + 16] + gv1*ab1;
      }
    }
  }
}

// ---------------------------------------------------------------------------
extern "C" void kernel_launch(void* const* d_in, const int* in_sizes, int n_in,
                              void* d_out, int out_size, void* d_ws, size_t ws_size,
                              hipStream_t stream)
{
  (void)in_sizes; (void)n_in; (void)out_size; (void)ws_size;
  const float* Zraw  = (const float*)d_in[0];
  const float* Zmask = (const float*)d_in[1];
  const float* g1    = (const float*)d_in[2];
  const float* b1    = (const float*)d_in[3];
  const float* Wlr   = (const float*)d_in[4];
  const float* blr   = (const float*)d_in[5];
  const float* Wg    = (const float*)d_in[6];
  const float* bg    = (const float*)d_in[7];
  const float* Wog   = (const float*)d_in[8];
  const float* bog   = (const float*)d_in[9];
  const float* g2    = (const float*)d_in[10];
  const float* b2    = (const float*)d_in[11];
  const float* Wout  = (const float*)d_in[12];
  const float* obias = (const float*)d_in[13];

  char* ws = (char*)d_ws;
  unsigned short* leftT  = (unsigned short*)(ws);
  unsigned short* rightT = (unsigned short*)(ws + 67108864L);
  unsigned short* pP     = (unsigned short*)(ws + 134217728L);
  unsigned short* Wc     = (unsigned short*)(ws + 201326592L);
  float* svec            = (float*)(ws + 201326592L + 196608L);
  float* cvec            = (float*)(ws + 201326592L + 196608L + 4096L);
  float* out = (float*)d_out;

  k_prep<<<192, 256, 0, stream>>>(Wlr, blr, Wg, bg, Wog, bog, Wout, obias,
                                  g1, b1, g2, b2, Wc, svec, cvec);
  k_proj<<<4096, 256, 0, stream>>>(Zraw, Zmask, Wc, svec, cvec, leftT, rightT);
  k_tri<<<2048, 256, 0, stream>>>(leftT, rightT, pP);
  k_out<<<2048, 256, 0, stream>>>(Zraw, pP, Wc, svec, cvec, out);
}